// Round 6
// baseline (494.098 us; speedup 1.0000x reference)
//
#include <hip/hip_runtime.h>
#include <math.h>

#define BATCH 8
#define CH    256
#define HWPIX 4096
#define CQK_  32

typedef __bf16 bf16x8 __attribute__((ext_vector_type(8)));
typedef __bf16 bf16x4 __attribute__((ext_vector_type(4)));
typedef float  f32x4  __attribute__((ext_vector_type(4)));

// load 8 consecutive fp32 from a W row, convert to bf16x8 fragment (k = quad*8+j)
static __device__ inline bf16x8 w_frag(const float* p) {
  const float4 a = *(const float4*)p;
  const float4 b = *(const float4*)(p + 4);
  bf16x8 r;
  r[0] = (__bf16)a.x; r[1] = (__bf16)a.y; r[2] = (__bf16)a.z; r[3] = (__bf16)a.w;
  r[4] = (__bf16)b.x; r[5] = (__bf16)b.y; r[6] = (__bf16)b.z; r[7] = (__bf16)b.w;
  return r;
}

// load 8 HWPIX-strided fp32 (8 consecutive input channels at one pixel) -> bf16x8
static __device__ inline bf16x8 f_frag(const float* p) {
  bf16x8 r;
#pragma unroll
  for (int j = 0; j < 8; ++j) r[j] = (__bf16)p[(size_t)j * HWPIX];
  return r;
}

// ---- Q/K projection, barrier-free direct-fragment MFMA.
// grid (64 n-tiles, 8 b), block 256 = 4 waves; wave w owns n rows 16w+[0,16).
// D = A(f^T rows n) * B(W rows o).  qT/kT layout: [b][n][32] bf16.
__global__ __launch_bounds__(256, 6) void proj_qk(
    const float* __restrict__ f1, const float* __restrict__ f2,
    const float* __restrict__ wq, const float* __restrict__ bq,
    const float* __restrict__ wk, const float* __restrict__ bk,
    __bf16* __restrict__ qT, __bf16* __restrict__ kT)
{
  const int t    = threadIdx.x;
  const int w    = __builtin_amdgcn_readfirstlane(t >> 6);
  const int lane = t & 63;
  const int q16  = lane & 15;
  const int quad = lane >> 4;
  const int b    = blockIdx.y;
  const int nrow = blockIdx.x * 64 + 16 * w + q16;

  const float* f1b = f1 + (size_t)b * CH * HWPIX + nrow;
  const float* f2b = f2 + (size_t)b * CH * HWPIX + nrow;

  f32x4 aQ[2], aK[2];
#pragma unroll
  for (int i = 0; i < 2; ++i) {
    aQ[i] = (f32x4){0.f, 0.f, 0.f, 0.f};
    aK[i] = (f32x4){0.f, 0.f, 0.f, 0.f};
  }

  for (int c0 = 0; c0 < CH; c0 += 64) {
#pragma unroll
    for (int kh = 0; kh < 2; ++kh) {
      const int cb = c0 + 32 * kh + quad * 8;
      const bf16x8 fa1 = f_frag(f1b + (size_t)cb * HWPIX);
      const bf16x8 fa2 = f_frag(f2b + (size_t)cb * HWPIX);
#pragma unroll
      for (int ot = 0; ot < 2; ++ot) {
        const bf16x8 wfq = w_frag(wq + (size_t)(16 * ot + q16) * CH + cb);
        aQ[ot] = __builtin_amdgcn_mfma_f32_16x16x32_bf16(fa1, wfq, aQ[ot], 0, 0, 0);
        const bf16x8 wfk = w_frag(wk + (size_t)(16 * ot + q16) * CH + cb);
        aK[ot] = __builtin_amdgcn_mfma_f32_16x16x32_bf16(fa2, wfk, aK[ot], 0, 0, 0);
      }
    }
  }

  // C-layout: row n-sub = quad*4+r, col o = 16ot+q16
#pragma unroll
  for (int ot = 0; ot < 2; ++ot) {
    const float bqv = bq[16 * ot + q16];
    const float bkv = bk[16 * ot + q16];
#pragma unroll
    for (int r = 0; r < 4; ++r) {
      const size_t row = (size_t)b * HWPIX + blockIdx.x * 64 + 16 * w + quad * 4 + r;
      qT[row * CQK_ + 16 * ot + q16] = (__bf16)(aQ[ot][r] + bqv);
      kT[row * CQK_ + 16 * ot + q16] = (__bf16)(aK[ot][r] + bkv);
    }
  }
}

// ---- V projection, barrier-free. grid (64 n-tiles, 8 b), block 256 = 4 waves.
// D = A(W_v rows c) * B(f3^T cols n); wave w owns n cols 16w+[0,16), all 256 c.
__global__ __launch_bounds__(256, 3) void proj_v(
    const float* __restrict__ f3, const float* __restrict__ wv,
    const float* __restrict__ bv, __bf16* __restrict__ vv)
{
  const int t    = threadIdx.x;
  const int w    = __builtin_amdgcn_readfirstlane(t >> 6);
  const int lane = t & 63;
  const int q16  = lane & 15;
  const int quad = lane >> 4;
  const int b    = blockIdx.y;
  const int nrow = blockIdx.x * 64 + 16 * w + q16;

  const float* f3b = f3 + (size_t)b * CH * HWPIX + nrow;

  f32x4 acc[16];
#pragma unroll
  for (int ct = 0; ct < 16; ++ct) acc[ct] = (f32x4){0.f, 0.f, 0.f, 0.f};

  for (int c0 = 0; c0 < CH; c0 += 64) {
#pragma unroll
    for (int kh = 0; kh < 2; ++kh) {
      const int cb = c0 + 32 * kh + quad * 8;
      const bf16x8 fb = f_frag(f3b + (size_t)cb * HWPIX);
#pragma unroll
      for (int ct = 0; ct < 16; ++ct) {
        const bf16x8 wf = w_frag(wv + (size_t)(16 * ct + q16) * CH + cb);
        acc[ct] = __builtin_amdgcn_mfma_f32_16x16x32_bf16(wf, fb, acc[ct], 0, 0, 0);
      }
    }
  }

  // C-layout: row c = 16ct + quad*4 + r, col n = nrow
#pragma unroll
  for (int ct = 0; ct < 16; ++ct) {
    const float4 bi = *(const float4*)&bv[16 * ct + quad * 4];
#pragma unroll
    for (int r = 0; r < 4; ++r) {
      const int c = 16 * ct + quad * 4 + r;
      vv[((size_t)b * CH + c) * HWPIX + nrow] = (__bf16)(acc[ct][r] + ((const float*)&bi)[r]);
    }
  }
}

// ---- Barrier-free flash attention: zero LDS, zero syncs, zero shuffles in loop.
// grid 512: b = bx&7 (XCD-pinned), q-tile = bx>>3 (64 q). block 256 = 4 waves.
// Each wave independently: scores S^T for all 64 q (recomputed), AV for its 64-c slice.
// Permuted-K trick: AV k-slot (quad,j) <-> key m = 32a + (j>=4)*16 + quad*4 + (j&3);
// applied identically to V (A) loads and P (B) packing, so P stays in registers.
__global__ __launch_bounds__(256, 2) void attn_kernel(
    const __bf16* __restrict__ qT, const __bf16* __restrict__ kT,
    const __bf16* __restrict__ vv, float* __restrict__ out)
{
  const int t    = threadIdx.x;
  const int w    = __builtin_amdgcn_readfirstlane(t >> 6);
  const int lane = t & 63;
  const int q16  = lane & 15;
  const int quad = lane >> 4;

  const int b  = blockIdx.x & 7;
  const int q0 = (blockIdx.x >> 3) * 64;

  const __bf16* kTb = kT + (size_t)b * HWPIX * CQK_;
  const __bf16* qTb = qT + ((size_t)b * HWPIX + q0) * CQK_;
  const __bf16* vb  = vv + ((size_t)b * CH + 64 * w) * HWPIX;

  // Q B-fragments (cols q = 16nt+q16, k = c = quad*8+j), loaded once
  bf16x8 qf[4];
#pragma unroll
  for (int nt = 0; nt < 4; ++nt)
    qf[nt] = *(const bf16x8*)(qTb + (size_t)(16 * nt + q16) * CQK_ + quad * 8);

  f32x4 oacc[4][4];  // [ct][nt]
#pragma unroll
  for (int i = 0; i < 4; ++i)
#pragma unroll
    for (int j = 0; j < 4; ++j) oacc[i][j] = (f32x4){0.f, 0.f, 0.f, 0.f};
  float Lp[4] = {0.f, 0.f, 0.f, 0.f};

  for (int m0 = 0; m0 < HWPIX; m0 += 64) {
    // V A-fragments, permuted-k: two b64 halves per (ct, a)
    bf16x4 vlo[4][2], vhi[4][2];
#pragma unroll
    for (int ct = 0; ct < 4; ++ct) {
      const __bf16* vr = vb + (size_t)(16 * ct + q16) * HWPIX + m0 + quad * 4;
#pragma unroll
      for (int a = 0; a < 2; ++a) {
        vlo[ct][a] = *(const bf16x4*)(vr + 32 * a);
        vhi[ct][a] = *(const bf16x4*)(vr + 32 * a + 16);
      }
    }

    // K A-fragments (rows m = 16mt+q16, k = c = quad*8+j)
    bf16x8 kf[4];
#pragma unroll
    for (int mt = 0; mt < 4; ++mt)
      kf[mt] = *(const bf16x8*)(kTb + (size_t)(m0 + 16 * mt + q16) * CQK_ + quad * 8);

    // S^T[m][q]: rows m (16mt + quad*4 + r), cols q (16nt + q16)
    f32x4 E[4][4];  // [mt][nt]
#pragma unroll
    for (int mt = 0; mt < 4; ++mt)
#pragma unroll
      for (int nt = 0; nt < 4; ++nt)
        E[mt][nt] = __builtin_amdgcn_mfma_f32_16x16x32_bf16(
            kf[mt], qf[nt], (f32x4){0.f, 0.f, 0.f, 0.f}, 0, 0, 0);

    // exp + lane-local pack into AV B-fragments (permuted-k order)
    bf16x8 pf[4][2];  // [nt][a]
#pragma unroll
    for (int nt = 0; nt < 4; ++nt) {
#pragma unroll
      for (int a = 0; a < 2; ++a) {
#pragma unroll
        for (int j = 0; j < 4; ++j) {
          const float e0 = __expf(E[2 * a][nt][j]);       // m = 32a + quad*4 + j
          Lp[nt] += e0;
          pf[nt][a][j] = (__bf16)e0;
          const float e1 = __expf(E[2 * a + 1][nt][j]);   // m = 32a + 16 + quad*4 + j
          Lp[nt] += e1;
          pf[nt][a][4 + j] = (__bf16)e1;
        }
      }
    }

    // AV: oacc[ct][nt] += V_perm (A) * P_perm (B)
#pragma unroll
    for (int ct = 0; ct < 4; ++ct)
#pragma unroll
      for (int a = 0; a < 2; ++a) {
        const bf16x8 vf = __builtin_shufflevector(vlo[ct][a], vhi[ct][a],
                                                  0, 1, 2, 3, 4, 5, 6, 7);
#pragma unroll
        for (int nt = 0; nt < 4; ++nt)
          oacc[ct][nt] = __builtin_amdgcn_mfma_f32_16x16x32_bf16(
              vf, pf[nt][a], oacc[ct][nt], 0, 0, 0);
      }
  }

  // L: every wave computed the full key sweep; reduce across quads (butterfly)
  float rinv[4];
#pragma unroll
  for (int nt = 0; nt < 4; ++nt) {
    float L = Lp[nt];
    L += __shfl_xor(L, 16);
    L += __shfl_xor(L, 32);
    rinv[nt] = 1.0f / L;
  }

  // store: row c = 64w + 16ct + quad*4 + r, col q = q0 + 16nt + q16
  float* ob = out + ((size_t)b * CH + 64 * w) * HWPIX + q0;
#pragma unroll
  for (int ct = 0; ct < 4; ++ct)
#pragma unroll
    for (int r = 0; r < 4; ++r)
#pragma unroll
      for (int nt = 0; nt < 4; ++nt)
        ob[(size_t)(16 * ct + quad * 4 + r) * HWPIX + 16 * nt + q16] =
            oacc[ct][nt][r] * rinv[nt];
}

extern "C" void kernel_launch(void* const* d_in, const int* in_sizes, int n_in,
                              void* d_out, int out_size, void* d_ws, size_t ws_size,
                              hipStream_t stream)
{
  const float* f1 = (const float*)d_in[0];
  const float* f2 = (const float*)d_in[1];
  const float* f3 = (const float*)d_in[2];
  const float* wq = (const float*)d_in[3];
  const float* bq = (const float*)d_in[4];
  const float* wk = (const float*)d_in[5];
  const float* bk = (const float*)d_in[6];
  const float* wv = (const float*)d_in[7];
  const float* bv = (const float*)d_in[8];
  float* outp = (float*)d_out;

  // workspace: qT [8][4096][32] | kT [8][4096][32] | v [8][256][4096]  (bf16, 20 MB)
  __bf16* qTw = (__bf16*)d_ws;
  __bf16* kTw = qTw + (size_t)BATCH * HWPIX * CQK_;
  __bf16* vw  = kTw + (size_t)BATCH * HWPIX * CQK_;

  proj_qk<<<dim3(64, 8), 256, 0, stream>>>(f1, f2, wq, bq, wk, bk, qTw, kTw);
  proj_v <<<dim3(64, 8), 256, 0, stream>>>(f3, wv, bv, vw);
  attn_kernel<<<dim3(512), 256, 0, stream>>>(qTw, kTw, vw, outp);
}